// Round 7
// baseline (302.563 us; speedup 1.0000x reference)
//
#include <hip/hip_runtime.h>
#include <math.h>

// Problem constants (from setup_inputs): B=8, J=4, N=4, M=16, K=3, D=32768
constexpr int B_ = 8;
constexpr int J_ = 4;
constexpr int N_ = 4;
constexpr int M_ = 16;
constexpr int K_ = 3;
constexpr int D_ = 32768;
constexpr float EPS_ = 1e-8f;
constexpr float TEMP_INV = 2.0f;   // 1/TEMP, TEMP=0.5

constexpr int NEG_V = B_ * N_ * M_ * K_;    // 1536 neg vectors
constexpr int POS_V = B_ * K_;              // 24 pos vectors
constexpr int SEG = 16;                     // D split into 16 segments
constexpr int SEG_F4 = D_ / 4 / SEG;        // 512 float4 per segment
constexpr int F4_PER_THR = SEG_F4 / 256;    // 2 float4 per thread
constexpr int NEG_GROUPS = B_ * N_ * K_;    // 96 groups of M=16 vectors
constexpr int NEG_BLOCKS = NEG_GROUPS * SEG;   // 1536
constexpr int POS_BLOCKS = POS_V * SEG;        // 384
constexpr int TOT_BLOCKS = NEG_BLOCKS + POS_BLOCKS;  // 1920

#define FMA4(acc, p, q) \
  acc += (p).x * (q).x + (p).y * (q).y + (p).z * (q).z + (p).w * (q).w

// ---------------------------------------------------------------------------
// Kernel A (atomic-free, R6 confirmed ~45ns/agent-RMW so no atomics ever):
// one neg block = one (b,n,k,seg) -> holds the x-segment in registers and
// streams ALL M=16 v-segments against it. Logical traffic drops from
// 2x fmaps_neg (403 MB; x re-read 64x) to 1.06x (214 MB), and the 16
// independent v-streams per thread provide MLP without fighting the
// register allocator. Partials -> unique ws slots via plain stores.
// ---------------------------------------------------------------------------
__global__ __launch_bounds__(256) void partial_kernel(
    const float* __restrict__ fmaps, const float* __restrict__ fmaps_pos,
    const float* __restrict__ fmaps_neg,
    float* __restrict__ neg_dot_p, float* __restrict__ neg_nv_p,
    float* __restrict__ pos_dot_p, float* __restrict__ pos_nx_p,
    float* __restrict__ pos_np_p) {
  __shared__ float sred[3][4];
  const int t = threadIdx.x;
  const int wid = t >> 6, lane = t & 63;

  if (blockIdx.x < NEG_BLOCKS) {
    // ---- neg group: g = (b*N + n)*K + k ; covers m = 0..15 ----
    const int g = blockIdx.x / SEG;
    const int seg = blockIdx.x % SEG;
    const int b = g / (N_ * K_);
    const int r = g % (N_ * K_);
    const int n = r / K_;
    const int k = r % K_;

    const size_t xbase = (((size_t)b * J_ + (J_ - 1)) * K_ + k) * (size_t)D_;
    const float4* __restrict__ xs =
        (const float4*)(fmaps + xbase) + (size_t)seg * SEG_F4;
    // v vector for m: (((b*N+n)*M + m)*K + k)*D ; stride between m = K*D
    const size_t vbase0 = ((((size_t)b * N_ + n) * M_ + 0) * K_ + k) * (size_t)D_;
    const float4* __restrict__ vs0 =
        (const float4*)(fmaps_neg + vbase0) + (size_t)seg * SEG_F4;
    constexpr size_t M_STRIDE_F4 = (size_t)K_ * D_ / 4;  // 24576 float4

    const float4 a0 = xs[t];
    const float4 a1 = xs[t + 256];

    float dot[M_], nv[M_];
#pragma unroll
    for (int m = 0; m < M_; ++m) {
      const float4* __restrict__ vm = vs0 + (size_t)m * M_STRIDE_F4;
      float4 c0 = vm[t];
      float4 c1 = vm[t + 256];
      float d = 0.f, q = 0.f;
      FMA4(d, a0, c0); FMA4(d, a1, c1);
      FMA4(q, c0, c0); FMA4(q, c1, c1);
      dot[m] = d; nv[m] = q;
    }

    // 32 wave-reductions, then cross-wave via LDS
#pragma unroll
    for (int m = 0; m < M_; ++m) {
      float d = dot[m], q = nv[m];
      for (int off = 32; off > 0; off >>= 1) {
        d += __shfl_down(d, off, 64);
        q += __shfl_down(q, off, 64);
      }
      if (lane == 0) { sred[0][wid] = d; sred[1][wid] = q; }
      __syncthreads();
      if (t == 0) {
        // storage index: (g, m, seg)
        const int sidx = (g * M_ + m) * SEG + seg;
        neg_dot_p[sidx] = sred[0][0] + sred[0][1] + sred[0][2] + sred[0][3];
        neg_nv_p[sidx]  = sred[1][0] + sred[1][1] + sred[1][2] + sred[1][3];
      }
      __syncthreads();
    }
  } else {
    // ---- pos partial: vid = b*K + k ----
    const int pid = blockIdx.x - NEG_BLOCKS;
    const int vid = pid / SEG;
    const int seg = pid % SEG;
    const int b = vid / K_, k = vid % K_;
    const size_t base = (((size_t)b * J_ + (J_ - 1)) * K_ + k) * (size_t)D_;
    const float4* __restrict__ xs =
        (const float4*)(fmaps + base) + (size_t)seg * SEG_F4;
    const float4* __restrict__ ps =
        (const float4*)(fmaps_pos + base) + (size_t)seg * SEG_F4;

    float dot = 0.f, nx = 0.f, np = 0.f;
#pragma unroll
    for (int u = 0; u < F4_PER_THR; ++u) {
      float4 a = xs[t + 256 * u];
      float4 c = ps[t + 256 * u];
      FMA4(dot, a, c);
      FMA4(nx, a, a);
      FMA4(np, c, c);
    }
    for (int off = 32; off > 0; off >>= 1) {
      dot += __shfl_down(dot, off, 64);
      nx  += __shfl_down(nx,  off, 64);
      np  += __shfl_down(np,  off, 64);
    }
    if (lane == 0) { sred[0][wid] = dot; sred[1][wid] = nx; sred[2][wid] = np; }
    __syncthreads();
    if (t == 0) {
      pos_dot_p[pid] = sred[0][0] + sred[0][1] + sred[0][2] + sred[0][3];
      pos_nx_p[pid]  = sred[1][0] + sred[1][1] + sred[1][2] + sred[1][3];
      pos_np_p[pid]  = sred[2][0] + sred[2][1] + sred[2][2] + sred[2][3];
    }
  }
}

// ---------------------------------------------------------------------------
// Kernel B: single block. Sum the SEG partials per vector, form cosines in
// LDS, masked logsumexp, final scalar.
// ---------------------------------------------------------------------------
__global__ __launch_bounds__(256) void finish_kernel(
    const float* __restrict__ neg_dot_p, const float* __restrict__ neg_nv_p,
    const float* __restrict__ pos_dot_p, const float* __restrict__ pos_nx_p,
    const float* __restrict__ pos_np_p,
    const int* __restrict__ gt_labels, const int* __restrict__ gt_label_negs,
    float* __restrict__ out) {
  __shared__ float l_neg[NEG_V];   // indexed by logical ((b*N+n)*M+m)*K+k
  __shared__ float l_pos[POS_V];
  __shared__ float l_nxs[POS_V];
  __shared__ float red[4];
  const int t = threadIdx.x;

  // pos logits + |x| per (b,k)
  if (t < POS_V) {
    float dot = 0.f, nx = 0.f, np = 0.f;
    for (int s2 = 0; s2 < SEG; ++s2) {
      dot += pos_dot_p[t * SEG + s2];
      nx  += pos_nx_p[t * SEG + s2];
      np  += pos_np_p[t * SEG + s2];
    }
    const float nxs = sqrtf(nx);
    l_nxs[t] = nxs;
    l_pos[t] = dot / fmaxf(nxs * sqrtf(np), EPS_) * TEMP_INV;
  }
  __syncthreads();

  // neg logits: storage order sidx = (g*M + m)*SEG + seg, g = (b*N+n)*K + k
  for (int sv = t; sv < NEG_V; sv += 256) {   // sv = g*M + m
    float dot = 0.f, nv = 0.f;
    for (int s2 = 0; s2 < SEG; ++s2) {
      dot += neg_dot_p[sv * SEG + s2];
      nv  += neg_nv_p[sv * SEG + s2];
    }
    const int g = sv / M_, m = sv % M_;
    const int b = g / (N_ * K_);
    const int r = g % (N_ * K_);
    const int n = r / K_;
    const int k = r % K_;
    const int lidx = (((b * N_ + n) * M_) + m) * K_ + k;
    l_neg[lidx] = dot / fmaxf(l_nxs[b * K_ + k] * sqrtf(nv), EPS_) * TEMP_INV;
  }
  __syncthreads();

  // masked logsumexp: 8 threads per (b,k). Logits bounded in [-2,2]
  // (cosine/TEMP) so no max-shift needed.
  const int bk = t >> 3, sub = t & 7;
  float partial = 0.f;
  if (bk < POS_V) {
    const int b = bk / K_, k = bk % K_;
    const int lbl = gt_labels[b * J_ + (J_ - 1)];
    for (int u = 0; u < 8; ++u) {
      const int i = sub * 8 + u;                  // n*M+m in 0..63
      if (gt_label_negs[b * (N_ * M_) + i] == lbl) {
        partial += expf(l_neg[(b * (N_ * M_) + i) * K_ + k]);
      }
    }
  }
  for (int off = 1; off < 8; off <<= 1) partial += __shfl_xor(partial, off, 64);

  float contrib = 0.f;
  if (bk < POS_V && sub == 0) {
    const float p = l_pos[bk];
    contrib = logf(partial + expf(p)) - p;
  }
  for (int off = 32; off > 0; off >>= 1) contrib += __shfl_down(contrib, off, 64);
  const int wid = t >> 6, lane = t & 63;
  if (lane == 0) red[wid] = contrib;
  __syncthreads();
  if (t == 0) out[0] = (red[0] + red[1] + red[2] + red[3]) / (2.0f * (float)B_);
}

// ---------------------------------------------------------------------------
extern "C" void kernel_launch(void* const* d_in, const int* in_sizes, int n_in,
                              void* d_out, int out_size, void* d_ws, size_t ws_size,
                              hipStream_t stream) {
  const float* fmaps         = (const float*)d_in[0];
  const float* fmaps_pos     = (const float*)d_in[1];
  const float* fmaps_neg     = (const float*)d_in[2];
  const int*   gt_labels     = (const int*)d_in[3];
  const int*   gt_label_negs = (const int*)d_in[4];
  float* out = (float*)d_out;

  // ws layout (floats), unique slots, plain stores, no init needed:
  // [0, 24576)        neg_dot_p   (NEG_V * SEG)
  // [24576, 49152)    neg_nv_p
  // [49152, 49536)    pos_dot_p   (POS_V * SEG)
  // [49536, 49920)    pos_nx_p
  // [49920, 50304)    pos_np_p
  float* ws        = (float*)d_ws;
  float* neg_dot_p = ws;
  float* neg_nv_p  = ws + NEG_V * SEG;
  float* pos_dot_p = ws + 2 * NEG_V * SEG;
  float* pos_nx_p  = ws + 2 * NEG_V * SEG + POS_V * SEG;
  float* pos_np_p  = ws + 2 * NEG_V * SEG + 2 * POS_V * SEG;

  partial_kernel<<<TOT_BLOCKS, 256, 0, stream>>>(
      fmaps, fmaps_pos, fmaps_neg,
      neg_dot_p, neg_nv_p, pos_dot_p, pos_nx_p, pos_np_p);
  finish_kernel<<<1, 256, 0, stream>>>(
      neg_dot_p, neg_nv_p, pos_dot_p, pos_nx_p, pos_np_p,
      gt_labels, gt_label_negs, out);
}

// Round 8
// 294.717 us; speedup vs baseline: 1.0266x; 1.0266x over previous
//
#include <hip/hip_runtime.h>
#include <math.h>

// Problem constants (from setup_inputs): B=8, J=4, N=4, M=16, K=3, D=32768
constexpr int B_ = 8;
constexpr int J_ = 4;
constexpr int N_ = 4;
constexpr int M_ = 16;
constexpr int K_ = 3;
constexpr int D_ = 32768;
constexpr float EPS_ = 1e-8f;
constexpr float TEMP_INV = 2.0f;   // 1/TEMP, TEMP=0.5

constexpr int NEG_V = B_ * N_ * M_ * K_;    // 1536 neg vectors
constexpr int POS_V = B_ * K_;              // 24 pos vectors
constexpr int SEG = 8;                      // D split into 8 segments
constexpr int SEG_F4 = D_ / 4 / SEG;        // 1024 float4 per segment
constexpr int MG = 8;                       // m's per neg block
constexpr int NEG_GROUPS = B_ * N_ * K_;    // 96 (b,n,k) groups
constexpr int NEG_BLOCKS = NEG_GROUPS * (M_ / MG) * SEG;  // 96*2*8 = 1536
constexpr int POS_BLOCKS = POS_V * SEG;                    // 192
constexpr int TOT_BLOCKS = NEG_BLOCKS + POS_BLOCKS;        // 1728

// LDS row padded 256->272: transpose-read groups offset by 16 banks ->
// 2-way conflicts only (free, m136).
constexpr int LROW = 272;

#define FMA4(acc, p, q) \
  acc += (p).x * (q).x + (p).y * (q).y + (p).z * (q).z + (p).w * (q).w

// ---------------------------------------------------------------------------
// Kernel A (atomic-free; R5 showed ~45ns/agent-RMW chains). Neg block =
// (b,n,k,mg,seg): x-segment (4 float4) pinned in registers, streams MG=8
// v-segments against it -> logical traffic 400->~240 MB vs R6. Reduction is
// ONE LDS transpose round-trip (16 writes + 2 barriers + 16 reads + 4
// shuffles) instead of R7's 192 shuffles + 32 barriers, which ate R7's win.
// ---------------------------------------------------------------------------
__global__ __launch_bounds__(256) void partial_kernel(
    const float* __restrict__ fmaps, const float* __restrict__ fmaps_pos,
    const float* __restrict__ fmaps_neg,
    float* __restrict__ neg_dot_p, float* __restrict__ neg_nv_p,
    float* __restrict__ pos_dot_p, float* __restrict__ pos_nx_p,
    float* __restrict__ pos_np_p) {
  __shared__ float lds[2 * MG][LROW];
  const int t = threadIdx.x;

  if (blockIdx.x < NEG_BLOCKS) {
    // ---- neg: decode (g, mg, seg); g = (b*N + n)*K + k ----
    const int seg = blockIdx.x % SEG;
    const int rest = blockIdx.x / SEG;         // [0, 192)
    const int mg = rest % (M_ / MG);           // 0 or 1
    const int g = rest / (M_ / MG);            // [0, 96)
    const int b = g / (N_ * K_);
    const int r = g % (N_ * K_);
    const int n = r / K_;
    const int k = r % K_;

    const size_t xbase = (((size_t)b * J_ + (J_ - 1)) * K_ + k) * (size_t)D_;
    const float4* __restrict__ xs =
        (const float4*)(fmaps + xbase) + (size_t)seg * SEG_F4;
    // v for m: (((b*N+n)*M + m)*K + k)*D ; stride between m = K*D floats
    const size_t vbase =
        ((((size_t)b * N_ + n) * M_ + (size_t)mg * MG) * K_ + k) * (size_t)D_;
    const float4* __restrict__ vs0 =
        (const float4*)(fmaps_neg + vbase) + (size_t)seg * SEG_F4;
    constexpr size_t M_STRIDE_F4 = (size_t)K_ * D_ / 4;  // 24576

    float4 a0 = xs[t];
    float4 a1 = xs[t + 256];
    float4 a2 = xs[t + 512];
    float4 a3 = xs[t + 768];

    float dot[MG], nv[MG];
#pragma unroll
    for (int j = 0; j < MG; ++j) {
      const float4* __restrict__ vm = vs0 + (size_t)j * M_STRIDE_F4;
      float4 c0 = vm[t];
      float4 c1 = vm[t + 256];
      float4 c2 = vm[t + 512];
      float4 c3 = vm[t + 768];
      float d = 0.f, q = 0.f;
      FMA4(d, a0, c0); FMA4(d, a1, c1); FMA4(d, a2, c2); FMA4(d, a3, c3);
      FMA4(q, c0, c0); FMA4(q, c1, c1); FMA4(q, c2, c2); FMA4(q, c3, c3);
      dot[j] = d; nv[j] = q;
    }

    // ---- LDS-transpose reduction: 16 outputs, 16 threads each ----
#pragma unroll
    for (int j = 0; j < MG; ++j) {
      lds[j][t]      = dot[j];
      lds[MG + j][t] = nv[j];
    }
    __syncthreads();
    const int outi = t >> 4;       // 0..15
    const int l16  = t & 15;
    float sum = 0.f;
#pragma unroll
    for (int i = 0; i < 16; ++i) sum += lds[outi][l16 + 16 * i];
    // reduce the 16-lane subgroup (contiguous lanes within a wave)
    for (int off = 1; off < 16; off <<= 1) sum += __shfl_xor(sum, off, 64);
    if (l16 == 0) {
      const int m = mg * MG + (outi & (MG - 1));
      const int sv = g * M_ + m;                 // storage vector id
      const int sidx = sv * SEG + seg;
      if (outi < MG) neg_dot_p[sidx] = sum;
      else           neg_nv_p[sidx]  = sum;
    }
  } else {
    // ---- pos partial: vid = b*K + k ----
    const int pid = blockIdx.x - NEG_BLOCKS;
    const int vid = pid / SEG;
    const int seg = pid % SEG;
    const int b = vid / K_, k = vid % K_;
    const size_t base = (((size_t)b * J_ + (J_ - 1)) * K_ + k) * (size_t)D_;
    const float4* __restrict__ xs =
        (const float4*)(fmaps + base) + (size_t)seg * SEG_F4;
    const float4* __restrict__ ps =
        (const float4*)(fmaps_pos + base) + (size_t)seg * SEG_F4;

    float dot = 0.f, nx = 0.f, np = 0.f;
#pragma unroll
    for (int u = 0; u < SEG_F4 / 256; ++u) {   // 4 iters
      float4 a = xs[t + 256 * u];
      float4 c = ps[t + 256 * u];
      FMA4(dot, a, c);
      FMA4(nx, a, a);
      FMA4(np, c, c);
    }
    const int wid = t >> 6, lane = t & 63;
    for (int off = 32; off > 0; off >>= 1) {
      dot += __shfl_down(dot, off, 64);
      nx  += __shfl_down(nx,  off, 64);
      np  += __shfl_down(np,  off, 64);
    }
    if (lane == 0) { lds[0][wid] = dot; lds[1][wid] = nx; lds[2][wid] = np; }
    __syncthreads();
    if (t == 0) {
      pos_dot_p[pid] = lds[0][0] + lds[0][1] + lds[0][2] + lds[0][3];
      pos_nx_p[pid]  = lds[1][0] + lds[1][1] + lds[1][2] + lds[1][3];
      pos_np_p[pid]  = lds[2][0] + lds[2][1] + lds[2][2] + lds[2][3];
    }
  }
}

// ---------------------------------------------------------------------------
// Kernel B: single block. Sum SEG partials per vector, cosines in LDS,
// masked logsumexp, final scalar.
// ---------------------------------------------------------------------------
__global__ __launch_bounds__(256) void finish_kernel(
    const float* __restrict__ neg_dot_p, const float* __restrict__ neg_nv_p,
    const float* __restrict__ pos_dot_p, const float* __restrict__ pos_nx_p,
    const float* __restrict__ pos_np_p,
    const int* __restrict__ gt_labels, const int* __restrict__ gt_label_negs,
    float* __restrict__ out) {
  __shared__ float l_neg[NEG_V];   // logical index ((b*N+n)*M+m)*K+k
  __shared__ float l_pos[POS_V];
  __shared__ float l_nxs[POS_V];
  __shared__ float red[4];
  const int t = threadIdx.x;

  if (t < POS_V) {
    float dot = 0.f, nx = 0.f, np = 0.f;
    for (int s2 = 0; s2 < SEG; ++s2) {
      dot += pos_dot_p[t * SEG + s2];
      nx  += pos_nx_p[t * SEG + s2];
      np  += pos_np_p[t * SEG + s2];
    }
    const float nxs = sqrtf(nx);
    l_nxs[t] = nxs;
    l_pos[t] = dot / fmaxf(nxs * sqrtf(np), EPS_) * TEMP_INV;
  }
  __syncthreads();

  // neg: storage sv = g*M + m, g = (b*N+n)*K + k
  for (int sv = t; sv < NEG_V; sv += 256) {
    float dot = 0.f, nv = 0.f;
    for (int s2 = 0; s2 < SEG; ++s2) {
      dot += neg_dot_p[sv * SEG + s2];
      nv  += neg_nv_p[sv * SEG + s2];
    }
    const int g = sv / M_, m = sv % M_;
    const int b = g / (N_ * K_);
    const int r = g % (N_ * K_);
    const int n = r / K_;
    const int k = r % K_;
    const int lidx = ((b * N_ + n) * M_ + m) * K_ + k;
    l_neg[lidx] = dot / fmaxf(l_nxs[b * K_ + k] * sqrtf(nv), EPS_) * TEMP_INV;
  }
  __syncthreads();

  // masked logsumexp: 8 threads per (b,k); logits bounded in [-2,2].
  const int bk = t >> 3, sub = t & 7;
  float partial = 0.f;
  if (bk < POS_V) {
    const int b = bk / K_, k = bk % K_;
    const int lbl = gt_labels[b * J_ + (J_ - 1)];
    for (int u = 0; u < 8; ++u) {
      const int i = sub * 8 + u;                  // n*M+m in 0..63
      if (gt_label_negs[b * (N_ * M_) + i] == lbl) {
        partial += expf(l_neg[(b * (N_ * M_) + i) * K_ + k]);
      }
    }
  }
  for (int off = 1; off < 8; off <<= 1) partial += __shfl_xor(partial, off, 64);

  float contrib = 0.f;
  if (bk < POS_V && sub == 0) {
    const float p = l_pos[bk];
    contrib = logf(partial + expf(p)) - p;
  }
  for (int off = 32; off > 0; off >>= 1) contrib += __shfl_down(contrib, off, 64);
  const int wid = t >> 6, lane = t & 63;
  if (lane == 0) red[wid] = contrib;
  __syncthreads();
  if (t == 0) out[0] = (red[0] + red[1] + red[2] + red[3]) / (2.0f * (float)B_);
}

// ---------------------------------------------------------------------------
extern "C" void kernel_launch(void* const* d_in, const int* in_sizes, int n_in,
                              void* d_out, int out_size, void* d_ws, size_t ws_size,
                              hipStream_t stream) {
  const float* fmaps         = (const float*)d_in[0];
  const float* fmaps_pos     = (const float*)d_in[1];
  const float* fmaps_neg     = (const float*)d_in[2];
  const int*   gt_labels     = (const int*)d_in[3];
  const int*   gt_label_negs = (const int*)d_in[4];
  float* out = (float*)d_out;

  // ws layout (floats), unique slots, plain stores, no init needed:
  // [0, 12288)        neg_dot_p   (NEG_V * SEG)
  // [12288, 24576)    neg_nv_p
  // [24576, 24768)    pos_dot_p   (POS_V * SEG)
  // [24768, 24960)    pos_nx_p
  // [24960, 25152)    pos_np_p
  float* ws        = (float*)d_ws;
  float* neg_dot_p = ws;
  float* neg_nv_p  = ws + NEG_V * SEG;
  float* pos_dot_p = ws + 2 * NEG_V * SEG;
  float* pos_nx_p  = ws + 2 * NEG_V * SEG + POS_V * SEG;
  float* pos_np_p  = ws + 2 * NEG_V * SEG + 2 * POS_V * SEG;

  partial_kernel<<<TOT_BLOCKS, 256, 0, stream>>>(
      fmaps, fmaps_pos, fmaps_neg,
      neg_dot_p, neg_nv_p, pos_dot_p, pos_nx_p, pos_np_p);
  finish_kernel<<<1, 256, 0, stream>>>(
      neg_dot_p, neg_nv_p, pos_dot_p, pos_nx_p, pos_np_p,
      gt_labels, gt_label_negs, out);
}

// Round 9
// 288.719 us; speedup vs baseline: 1.0480x; 1.0208x over previous
//
#include <hip/hip_runtime.h>
#include <math.h>

// Problem constants (from setup_inputs): B=8, J=4, N=4, M=16, K=3, D=32768
constexpr int B_ = 8;
constexpr int J_ = 4;
constexpr int N_ = 4;
constexpr int M_ = 16;
constexpr int K_ = 3;
constexpr int D_ = 32768;
constexpr float EPS_ = 1e-8f;
constexpr float TEMP_INV = 2.0f;   // 1/TEMP, TEMP=0.5

constexpr int NEG_V = B_ * N_ * M_ * K_;    // 1536 neg vectors
constexpr int POS_V = B_ * K_;              // 24 pos vectors
constexpr int SEG = 8;                      // D split into 8 segments
constexpr int SEG_FLT = D_ / SEG;           // 4096 floats / segment / stream
constexpr int NEG_BLOCKS = NEG_V * SEG;     // 12288
constexpr int POS_BLOCKS = POS_V * SEG;     // 192
constexpr int TOT_BLOCKS = NEG_BLOCKS + POS_BLOCKS;  // 12480

#define FMA4(acc, p, q) \
  acc += (p).x * (q).x + (p).y * (q).y + (p).z * (q).z + (p).w * (q).w

// Async global->LDS DMA, 16 B/lane (m97-proven: emits global_load_lds_dwordx4).
// LDS dest is wave-uniform base + lane*16; gptr is per-lane. Fire-and-forget:
// no destination VGPRs, so outstanding-load depth no longer depends on the
// register allocator (which collapsed every VGPR-batched attempt to ~4 in
// flight: R4 VGPR=32, R5 VGPR=36 -> the recurring latency bound).
__device__ __forceinline__ void dma16(const float* g, float* l) {
  __builtin_amdgcn_global_load_lds(
      (const __attribute__((address_space(1))) float*)g,
      (__attribute__((address_space(3))) float*)l, 16, 0, 0);
}

// ---------------------------------------------------------------------------
// Kernel A (atomic-free): block = one (vector, seg). Stage 16 KB a-seg +
// 16 KB c-seg into exactly 32 KB LDS via 8 DMAs/wave (8 KB in flight/wave,
// 5 blocks/CU -> 20 waves/CU -> ~160 KB in flight/CU), barrier (compiler
// emits vmcnt(0) drain), then ds_read_b128 + FMA + one shuffle reduction.
// ---------------------------------------------------------------------------
__global__ __launch_bounds__(256) void partial_kernel(
    const float* __restrict__ fmaps, const float* __restrict__ fmaps_pos,
    const float* __restrict__ fmaps_neg,
    float* __restrict__ neg_dot_p, float* __restrict__ neg_nv_p,
    float* __restrict__ pos_dot_p, float* __restrict__ pos_nx_p,
    float* __restrict__ pos_np_p) {
  __shared__ float lds[2 * SEG_FLT];   // 32768 B exactly: [0,4096)=a, [4096,8192)=c
  const int t = threadIdx.x;
  const int w = t >> 6, lane = t & 63;
  const int laneF = lane * 4;

  const bool isNeg = blockIdx.x < (unsigned)NEG_BLOCKS;
  const int id  = isNeg ? blockIdx.x : blockIdx.x - NEG_BLOCKS;
  const int vid = id / SEG;            // neg: ((b*N+n)*M+m)*K+k ; pos: b*K+k
  const int seg = id % SEG;
  const int k = vid % K_;
  const int b = isNeg ? vid / (N_ * M_ * K_) : vid / K_;

  const size_t xoff =
      (((size_t)b * J_ + (J_ - 1)) * K_ + k) * (size_t)D_ + (size_t)seg * SEG_FLT;
  const float* abase = fmaps + xoff;
  const float* cbase = isNeg
      ? (fmaps_neg + (size_t)vid * D_ + (size_t)seg * SEG_FLT)
      : (fmaps_pos + xoff);

  // ---- stage: each wave owns a contiguous 1024-float quarter of each stream
  const int wbase = w * (SEG_FLT / 4);   // 1024 floats
  {
    const float* ga = abase + wbase + laneF;
    const float* gc = cbase + wbase + laneF;
    float* la = lds + wbase;             // wave-uniform LDS base
    float* lc = lds + SEG_FLT + wbase;
#pragma unroll
    for (int i = 0; i < 4; ++i) {
      dma16(ga + i * 256, la + i * 256);   // each inst: 64 lanes x 16 B = 1 KB
      dma16(gc + i * 256, lc + i * 256);
    }
  }
  __syncthreads();   // compiler emits s_waitcnt vmcnt(0) before s_barrier

  // ---- compute: 4 float4 pairs per lane from LDS
  float dot = 0.f, s1 = 0.f, s2 = 0.f;  // s1 = nv(neg)/nx(pos); s2 = np(pos)
#pragma unroll
  for (int i = 0; i < 4; ++i) {
    float4 a = *(const float4*)(lds + wbase + i * 256 + laneF);
    float4 c = *(const float4*)(lds + SEG_FLT + wbase + i * 256 + laneF);
    FMA4(dot, a, c);
    if (isNeg) {
      FMA4(s1, c, c);
    } else {
      FMA4(s1, a, a);
      FMA4(s2, c, c);
    }
  }

  // ---- reduce: wave shuffle, then cross-wave via (reused) LDS
  for (int off = 32; off > 0; off >>= 1) {
    dot += __shfl_down(dot, off, 64);
    s1  += __shfl_down(s1,  off, 64);
    s2  += __shfl_down(s2,  off, 64);
  }
  __syncthreads();   // all LDS data reads done; safe to reuse as scratch
  if (lane == 0) { lds[w] = dot; lds[4 + w] = s1; lds[8 + w] = s2; }
  __syncthreads();
  if (t == 0) {
    const float rd = lds[0] + lds[1] + lds[2] + lds[3];
    const float r1 = lds[4] + lds[5] + lds[6] + lds[7];
    const float r2 = lds[8] + lds[9] + lds[10] + lds[11];
    if (isNeg) {
      neg_dot_p[id] = rd;   // id == vid*SEG + seg
      neg_nv_p[id]  = r1;
    } else {
      pos_dot_p[id] = rd;
      pos_nx_p[id]  = r1;
      pos_np_p[id]  = r2;
    }
  }
}

// ---------------------------------------------------------------------------
// Kernel B: single block. Sum SEG partials per vector, cosines in LDS,
// masked logsumexp, final scalar.
// ---------------------------------------------------------------------------
__global__ __launch_bounds__(256) void finish_kernel(
    const float* __restrict__ neg_dot_p, const float* __restrict__ neg_nv_p,
    const float* __restrict__ pos_dot_p, const float* __restrict__ pos_nx_p,
    const float* __restrict__ pos_np_p,
    const int* __restrict__ gt_labels, const int* __restrict__ gt_label_negs,
    float* __restrict__ out) {
  __shared__ float l_neg[NEG_V];   // logical index ((b*N+n)*M+m)*K+k
  __shared__ float l_pos[POS_V];
  __shared__ float l_nxs[POS_V];
  __shared__ float red[4];
  const int t = threadIdx.x;

  if (t < POS_V) {
    float dot = 0.f, nx = 0.f, np = 0.f;
    for (int s2 = 0; s2 < SEG; ++s2) {
      dot += pos_dot_p[t * SEG + s2];
      nx  += pos_nx_p[t * SEG + s2];
      np  += pos_np_p[t * SEG + s2];
    }
    const float nxs = sqrtf(nx);
    l_nxs[t] = nxs;
    l_pos[t] = dot / fmaxf(nxs * sqrtf(np), EPS_) * TEMP_INV;
  }
  __syncthreads();

  for (int vid = t; vid < NEG_V; vid += 256) {
    float dot = 0.f, nv = 0.f;
    for (int s2 = 0; s2 < SEG; ++s2) {
      dot += neg_dot_p[vid * SEG + s2];
      nv  += neg_nv_p[vid * SEG + s2];
    }
    const int k = vid % K_;
    const int b = vid / (N_ * M_ * K_);
    l_neg[vid] = dot / fmaxf(l_nxs[b * K_ + k] * sqrtf(nv), EPS_) * TEMP_INV;
  }
  __syncthreads();

  // masked logsumexp: 8 threads per (b,k); logits bounded in [-2,2].
  const int bk = t >> 3, sub = t & 7;
  float partial = 0.f;
  if (bk < POS_V) {
    const int b = bk / K_, k = bk % K_;
    const int lbl = gt_labels[b * J_ + (J_ - 1)];
    for (int u = 0; u < 8; ++u) {
      const int i = sub * 8 + u;                  // n*M+m in 0..63
      if (gt_label_negs[b * (N_ * M_) + i] == lbl) {
        partial += expf(l_neg[(b * (N_ * M_) + i) * K_ + k]);
      }
    }
  }
  for (int off = 1; off < 8; off <<= 1) partial += __shfl_xor(partial, off, 64);

  float contrib = 0.f;
  if (bk < POS_V && sub == 0) {
    const float p = l_pos[bk];
    contrib = logf(partial + expf(p)) - p;
  }
  for (int off = 32; off > 0; off >>= 1) contrib += __shfl_down(contrib, off, 64);
  const int wid = t >> 6, lane = t & 63;
  if (lane == 0) red[wid] = contrib;
  __syncthreads();
  if (t == 0) out[0] = (red[0] + red[1] + red[2] + red[3]) / (2.0f * (float)B_);
}

// ---------------------------------------------------------------------------
extern "C" void kernel_launch(void* const* d_in, const int* in_sizes, int n_in,
                              void* d_out, int out_size, void* d_ws, size_t ws_size,
                              hipStream_t stream) {
  const float* fmaps         = (const float*)d_in[0];
  const float* fmaps_pos     = (const float*)d_in[1];
  const float* fmaps_neg     = (const float*)d_in[2];
  const int*   gt_labels     = (const int*)d_in[3];
  const int*   gt_label_negs = (const int*)d_in[4];
  float* out = (float*)d_out;

  // ws layout (floats), unique slots, plain stores, no init needed:
  // [0, 12288)        neg_dot_p   (NEG_V * SEG)
  // [12288, 24576)    neg_nv_p
  // [24576, 24768)    pos_dot_p   (POS_V * SEG)
  // [24768, 24960)    pos_nx_p
  // [24960, 25152)    pos_np_p
  float* ws        = (float*)d_ws;
  float* neg_dot_p = ws;
  float* neg_nv_p  = ws + NEG_V * SEG;
  float* pos_dot_p = ws + 2 * NEG_V * SEG;
  float* pos_nx_p  = ws + 2 * NEG_V * SEG + POS_V * SEG;
  float* pos_np_p  = ws + 2 * NEG_V * SEG + 2 * POS_V * SEG;

  partial_kernel<<<TOT_BLOCKS, 256, 0, stream>>>(
      fmaps, fmaps_pos, fmaps_neg,
      neg_dot_p, neg_nv_p, pos_dot_p, pos_nx_p, pos_np_p);
  finish_kernel<<<1, 256, 0, stream>>>(
      neg_dot_p, neg_nv_p, pos_dot_p, pos_nx_p, pos_np_p,
      gt_labels, gt_label_negs, out);
}